// Round 1
// baseline (3676.582 us; speedup 1.0000x reference)
//
#include <hip/hip_runtime.h>

#define D 128
#define NPB 64   // nodes per MLP block
#define LDZ 132  // padded LDS row stride (floats); 132*4=528 B, 16B-aligned

// ---------------------------------------------------------------------------
// Edge scatter: aggr[dst] += relu(x[src] + edge_attr)
// One thread per (edge, 4-float chunk): 32 threads cover one edge's 128 feats.
// ---------------------------------------------------------------------------
__global__ __launch_bounds__(256) void gine_edge_kernel(
    const float* __restrict__ x, const int* __restrict__ ei,
    const float* __restrict__ ea, float* aggr, int E) {
  long long idx = (long long)blockIdx.x * 256 + threadIdx.x;
  long long total = (long long)E * 32;
  if (idx >= total) return;
  int e = (int)(idx >> 5);
  int c = ((int)idx & 31) << 2;
  int src = ei[e];
  int dst = ei[E + e];
  const float4 xv = *reinterpret_cast<const float4*>(x + (size_t)src * D + c);
  const float4 av = *reinterpret_cast<const float4*>(ea + (size_t)e * D + c);
  float4 m;
  m.x = fmaxf(xv.x + av.x, 0.0f);
  m.y = fmaxf(xv.y + av.y, 0.0f);
  m.z = fmaxf(xv.z + av.z, 0.0f);
  m.w = fmaxf(xv.w + av.w, 0.0f);
  float* base = aggr + (size_t)dst * D + c;
  atomicAdd(base + 0, m.x);
  atomicAdd(base + 1, m.y);
  atomicAdd(base + 2, m.z);
  atomicAdd(base + 3, m.w);
}

// ---------------------------------------------------------------------------
// Fused MLP: out = relu((1+eps)*x + aggr) @ W1 + b1) @ W2 + b2
// aggr may alias out (block reads only its own rows, writes at the end).
// Block: 256 threads, 64 nodes. Thread (tx=tid&31, ty=tid>>5) owns
// nodes ty*8..ty*8+7 x cols tx*4..tx*4+3 (8x4 register tile).
// ---------------------------------------------------------------------------
__global__ __launch_bounds__(256) void gine_mlp_kernel(
    const float* __restrict__ x, const float* aggr,
    const float* __restrict__ eps_p,
    const float* __restrict__ W1, const float* __restrict__ b1,
    const float* __restrict__ W2, const float* __restrict__ b2,
    float* out, int N) {
  __shared__ float zs[NPB][LDZ];
  const int tid = threadIdx.x;
  const int tx = tid & 31;
  const int ty = tid >> 5;
  const int n0 = blockIdx.x * NPB;
  const float epsp1 = 1.0f + eps_p[0];

  // Stage z = (1+eps)*x + aggr into LDS (coalesced float4 loads)
  for (int i = tid; i < NPB * 32; i += 256) {
    int node = i >> 5;
    int c = (i & 31) << 2;
    int g = n0 + node;
    float4 zv = make_float4(0.f, 0.f, 0.f, 0.f);
    if (g < N) {
      float4 xv = *reinterpret_cast<const float4*>(x + (size_t)g * D + c);
      float4 av = *reinterpret_cast<const float4*>(aggr + (size_t)g * D + c);
      zv.x = epsp1 * xv.x + av.x;
      zv.y = epsp1 * xv.y + av.y;
      zv.z = epsp1 * xv.z + av.z;
      zv.w = epsp1 * xv.w + av.w;
    }
    zs[node][c + 0] = zv.x;
    zs[node][c + 1] = zv.y;
    zs[node][c + 2] = zv.z;
    zs[node][c + 3] = zv.w;
  }
  __syncthreads();

  float acc[8][4];

  // ---- Layer 1: h = relu(z @ W1 + b1) ----
  {
    const float4 bv = *reinterpret_cast<const float4*>(b1 + tx * 4);
#pragma unroll
    for (int r = 0; r < 8; ++r) {
      acc[r][0] = bv.x; acc[r][1] = bv.y; acc[r][2] = bv.z; acc[r][3] = bv.w;
    }
    for (int k = 0; k < D; k += 4) {
      float4 w0 = *reinterpret_cast<const float4*>(W1 + (size_t)(k + 0) * D + tx * 4);
      float4 w1 = *reinterpret_cast<const float4*>(W1 + (size_t)(k + 1) * D + tx * 4);
      float4 w2 = *reinterpret_cast<const float4*>(W1 + (size_t)(k + 2) * D + tx * 4);
      float4 w3 = *reinterpret_cast<const float4*>(W1 + (size_t)(k + 3) * D + tx * 4);
#pragma unroll
      for (int r = 0; r < 8; ++r) {
        float4 zv = *reinterpret_cast<const float4*>(&zs[ty * 8 + r][k]);
        acc[r][0] += zv.x * w0.x + zv.y * w1.x + zv.z * w2.x + zv.w * w3.x;
        acc[r][1] += zv.x * w0.y + zv.y * w1.y + zv.z * w2.y + zv.w * w3.y;
        acc[r][2] += zv.x * w0.z + zv.y * w1.z + zv.z * w2.z + zv.w * w3.z;
        acc[r][3] += zv.x * w0.w + zv.y * w1.w + zv.z * w2.w + zv.w * w3.w;
      }
    }
  }
  __syncthreads();  // all zs reads done before overwrite

  // h (relu) -> zs
#pragma unroll
  for (int r = 0; r < 8; ++r) {
    float4 hv;
    hv.x = fmaxf(acc[r][0], 0.f);
    hv.y = fmaxf(acc[r][1], 0.f);
    hv.z = fmaxf(acc[r][2], 0.f);
    hv.w = fmaxf(acc[r][3], 0.f);
    *reinterpret_cast<float4*>(&zs[ty * 8 + r][tx * 4]) = hv;
  }
  __syncthreads();

  // ---- Layer 2: out = h @ W2 + b2 ----
  {
    const float4 bv = *reinterpret_cast<const float4*>(b2 + tx * 4);
#pragma unroll
    for (int r = 0; r < 8; ++r) {
      acc[r][0] = bv.x; acc[r][1] = bv.y; acc[r][2] = bv.z; acc[r][3] = bv.w;
    }
    for (int k = 0; k < D; k += 4) {
      float4 w0 = *reinterpret_cast<const float4*>(W2 + (size_t)(k + 0) * D + tx * 4);
      float4 w1 = *reinterpret_cast<const float4*>(W2 + (size_t)(k + 1) * D + tx * 4);
      float4 w2 = *reinterpret_cast<const float4*>(W2 + (size_t)(k + 2) * D + tx * 4);
      float4 w3 = *reinterpret_cast<const float4*>(W2 + (size_t)(k + 3) * D + tx * 4);
#pragma unroll
      for (int r = 0; r < 8; ++r) {
        float4 zv = *reinterpret_cast<const float4*>(&zs[ty * 8 + r][k]);
        acc[r][0] += zv.x * w0.x + zv.y * w1.x + zv.z * w2.x + zv.w * w3.x;
        acc[r][1] += zv.x * w0.y + zv.y * w1.y + zv.z * w2.y + zv.w * w3.y;
        acc[r][2] += zv.x * w0.z + zv.y * w1.z + zv.z * w2.z + zv.w * w3.z;
        acc[r][3] += zv.x * w0.w + zv.y * w1.w + zv.z * w2.w + zv.w * w3.w;
      }
    }
  }

  // store
#pragma unroll
  for (int r = 0; r < 8; ++r) {
    int g = n0 + ty * 8 + r;
    if (g < N) {
      float4 ov = make_float4(acc[r][0], acc[r][1], acc[r][2], acc[r][3]);
      *reinterpret_cast<float4*>(out + (size_t)g * D + tx * 4) = ov;
    }
  }
}

extern "C" void kernel_launch(void* const* d_in, const int* in_sizes, int n_in,
                              void* d_out, int out_size, void* d_ws, size_t ws_size,
                              hipStream_t stream) {
  const float* x   = (const float*)d_in[0];
  const int*   ei  = (const int*)d_in[1];
  const float* ea  = (const float*)d_in[2];
  const float* eps = (const float*)d_in[3];
  const float* W1  = (const float*)d_in[4];
  const float* b1  = (const float*)d_in[5];
  const float* W2  = (const float*)d_in[6];
  const float* b2  = (const float*)d_in[7];
  float* out = (float*)d_out;

  const int N = in_sizes[0] / D;
  const int E = in_sizes[1] / 2;

  // aggr lives in d_out (same [N,128] shape); zero it (harness poisons 0xAA)
  hipMemsetAsync(d_out, 0, (size_t)out_size * sizeof(float), stream);

  long long tot = (long long)E * 32;
  int eblocks = (int)((tot + 255) / 256);
  gine_edge_kernel<<<eblocks, 256, 0, stream>>>(x, ei, ea, out, E);

  int nblocks = (N + NPB - 1) / NPB;
  gine_mlp_kernel<<<nblocks, 256, 0, stream>>>(x, out, eps, W1, b1, W2, b2, out, N);
}